// Round 5
// baseline (561.651 us; speedup 1.0000x reference)
//
#include <hip/hip_runtime.h>

typedef unsigned short u16;
typedef unsigned int   u32;
typedef __attribute__((ext_vector_type(8)))  short short8;   // 8 bf16 (4 VGPRs)
typedef __attribute__((ext_vector_type(16))) float floatx16; // 32x32 MFMA C/D
typedef __attribute__((ext_vector_type(8)))  u16   u16x8;
typedef __attribute__((ext_vector_type(4)))  u16   u16x4;

__device__ __forceinline__ u16 f2b(float f) {
    u32 u = __float_as_uint(f);
    u = (u + 0x7FFFu + ((u >> 16) & 1u)) >> 16;
    return (u16)u;
}
__device__ __forceinline__ float b2f(u16 h) {
    return __uint_as_float(((u32)h) << 16);
}

// ================= fused weight-prep + layer-1 kernel ======================
__device__ __forceinline__ void f2b_block(const float* __restrict__ src,
                                          u16* __restrict__ dst, int blk) {
    int i = blk * 256 + threadIdx.x;
    float4 v = ((const float4*)src)[i];
    u16x4 o;
    o[0] = f2b(v.x); o[1] = f2b(v.y); o[2] = f2b(v.z); o[3] = f2b(v.w);
    *(u16x4*)&dst[i * 4] = o;
}

__device__ __forceinline__ void pad_block(const float* __restrict__ Wsrc, int rows,
                                          u16* __restrict__ Wdst,
                                          const float* __restrict__ bsrc,
                                          float* __restrict__ bdst, int blk) {
    int i = blk * 256 + threadIdx.x;        // 32768 total (128x1024/4)
    int idx = i * 4;
    int r = idx >> 10;
    int c = idx & 1023;
    u16x4 o;
    if (r < rows) {
        float4 v = *(const float4*)&Wsrc[r * 1024 + c];
        o[0] = f2b(v.x); o[1] = f2b(v.y); o[2] = f2b(v.z); o[3] = f2b(v.w);
    } else {
        o[0] = 0; o[1] = 0; o[2] = 0; o[3] = 0;
    }
    *(u16x4*)&Wdst[idx] = o;
    if (i < 128) bdst[i] = (i < rows) ? bsrc[i] : 0.f;
}

__device__ __forceinline__ void l1_block(const float* __restrict__ x,
                                         const float* __restrict__ W1,
                                         const float* __restrict__ b1,
                                         u16* __restrict__ h1, int blk) {
    const int t  = threadIdx.x;
    const int b0 = blk * 16;
    const int n0 = t * 8;
    float4 wreg[8]; float breg[8];
    const float4* W14 = (const float4*)W1;
#pragma unroll
    for (int i = 0; i < 8; ++i) { wreg[i] = W14[n0 + i]; breg[i] = b1[n0 + i]; }
    for (int r = 0; r < 16; ++r) {
        int b = b0 + r;
        float4 xv = ((const float4*)x)[b];
        u16x8 o;
#pragma unroll
        for (int i = 0; i < 8; ++i) {
            float s = xv.x * wreg[i].x + xv.y * wreg[i].y +
                      xv.z * wreg[i].z + xv.w * wreg[i].w + breg[i];
            s = fmaxf(s, 0.f);
            o[i] = f2b(s);
        }
        *(u16x8*)&h1[(size_t)b * 2048 + n0] = o;
    }
}

// blocks: W2 4096 | W31 2048 | W32 2048 | W41 1024 | W42 1024 |
//         W51p 128 | W52p 128 | bcat 8 | l1 1024   = 11528 total
__global__ __launch_bounds__(256)
void k_prep(const float* W2,  u16* W2b,
            const float* W31, u16* W31b,
            const float* W32, u16* W32b,
            const float* W41, u16* W41b,
            const float* W42, u16* W42b,
            const float* W51, u16* W51p, const float* b51, float* b51p,
            const float* W52, u16* W52p, const float* b52, float* b52p,
            const float* b31, const float* b32, float* b3c,
            const float* x, const float* W1, const float* b1, u16* h1) {
    int blk = blockIdx.x;
    if (blk < 4096) { f2b_block(W2, W2b, blk); return; }   blk -= 4096;
    if (blk < 2048) { f2b_block(W31, W31b, blk); return; } blk -= 2048;
    if (blk < 2048) { f2b_block(W32, W32b, blk); return; } blk -= 2048;
    if (blk < 1024) { f2b_block(W41, W41b, blk); return; } blk -= 1024;
    if (blk < 1024) { f2b_block(W42, W42b, blk); return; } blk -= 1024;
    if (blk < 128)  { pad_block(W51, 20, W51p, b51, b51p, blk); return; } blk -= 128;
    if (blk < 128)  { pad_block(W52, 11, W52p, b52, b52p, blk); return; } blk -= 128;
    if (blk < 8) {
        int i = blk * 256 + threadIdx.x;
        b3c[i] = (i < 1024) ? b31[i] : b32[i - 1024];
        return;
    }
    blk -= 8;
    l1_block(x, W1, b1, h1, blk);
}

// ================= main bf16 MFMA GEMM, BK=64 (R3 structure, occ=4) ========
// C[M,N] = act(A[M,K] @ W[N,K]^T + b). 128x128 tile, BK=64, 256 threads
// (4 waves; each wave 64x64 via 2x2 mfma_f32_32x32x16_bf16, 4 k-steps).
// global_load_lds (16B/lane) staging; LDS rows are 128 B (all 32 banks),
// chunks XOR-swizzled: physical chunk p at row r holds logical p ^ (r&7);
// staging realizes the swizzle by permuting WHICH lane loads which global
// chunk (address set unchanged -> coalescing unchanged).
// launch_bounds(256,4): ~124 unified regs (60 VGPR + 64 acc) and 32 KB LDS
// fit 4 blocks/CU -> 16 waves/CU for barrier-drain latency hiding.
// XCD-aware block swizzle keeps x-blocks sharing an A-strip on one XCD L2.
// Optional second GEMM (A2/W2/bias2/C2) selected for swizzled by >= split.
__global__ __launch_bounds__(256, 4)
void k_gemm(const u16* __restrict__ A, const u16* __restrict__ W,
            const float* __restrict__ bias, u16* __restrict__ C,
            int K, int lda, int ldc, int relu,
            const u16* A2, const u16* W2, const float* bias2, u16* C2,
            int split) {
    __shared__ __align__(16) u16 As[128 * 64];  // 16 KB
    __shared__ __align__(16) u16 Ws[128 * 64];  // 16 KB

    const int tid  = threadIdx.x;
    const int wave = tid >> 6;
    const int lane = tid & 63;

    // XCD swizzle (valid permutation when gridY % 8 == 0)
    int by, bx;
    {
        int flat = blockIdx.y * gridDim.x + blockIdx.x;
        int xcd  = flat & 7;
        int p    = flat >> 3;
        bx = p % gridDim.x;
        by = (p / gridDim.x) * 8 + xcd;
    }
    if (A2 != nullptr && by >= split) {
        A = A2; W = W2; bias = bias2; C = C2; by -= split;
    }
    const int bm = by * 128;
    const int bn = bx * 128;

    // staging: one wave-load covers 8 rows x 128 B. lane -> row lane>>3,
    // physical chunk lane&7, which must hold logical chunk (lane&7)^(lane>>3).
    const int srow = lane >> 3;                    // 0..7
    const int sg   = ((lane & 7) ^ srow) * 8;      // swizzled global k-elem offset

    const int wm    = (wave & 1) * 64;
    const int wn    = (wave >> 1) * 64;
    const int row32 = lane & 31;
    const int half  = lane >> 5;

    floatx16 acc[2][2];
#pragma unroll
    for (int i = 0; i < 2; ++i)
#pragma unroll
        for (int j = 0; j < 2; ++j)
#pragma unroll
            for (int r = 0; r < 16; ++r) acc[i][j][r] = 0.f;

    for (int k0 = 0; k0 < K; k0 += 64) {
#pragma unroll
        for (int i = 0; i < 4; ++i) {
            int ci = wave * 4 + i;              // 16 chunks of 8 rows
            int r  = ci * 8 + srow;
            const u16* ga = A + (size_t)(bm + r) * lda + k0 + sg;
            __builtin_amdgcn_global_load_lds(
                (const __attribute__((address_space(1))) void*)ga,
                (__attribute__((address_space(3))) void*)&As[ci * 512], 16, 0, 0);
            const u16* gw = W + (size_t)(bn + r) * K + k0 + sg;
            __builtin_amdgcn_global_load_lds(
                (const __attribute__((address_space(1))) void*)gw,
                (__attribute__((address_space(3))) void*)&Ws[ci * 512], 16, 0, 0);
        }
        __syncthreads();

#pragma unroll
        for (int s = 0; s < 4; ++s) {
            const int c = s * 2 + half;         // logical 16B chunk 0..7
            short8 a0, a1, b0, b1;
            {
                int r = wm + row32;
                a0 = *(const short8*)&As[r * 64 + ((c ^ (r & 7)) * 8)];
            }
            {
                int r = wm + 32 + row32;
                a1 = *(const short8*)&As[r * 64 + ((c ^ (r & 7)) * 8)];
            }
            {
                int r = wn + row32;
                b0 = *(const short8*)&Ws[r * 64 + ((c ^ (r & 7)) * 8)];
            }
            {
                int r = wn + 32 + row32;
                b1 = *(const short8*)&Ws[r * 64 + ((c ^ (r & 7)) * 8)];
            }
            acc[0][0] = __builtin_amdgcn_mfma_f32_32x32x16_bf16(a0, b0, acc[0][0], 0, 0, 0);
            acc[0][1] = __builtin_amdgcn_mfma_f32_32x32x16_bf16(a0, b1, acc[0][1], 0, 0, 0);
            acc[1][0] = __builtin_amdgcn_mfma_f32_32x32x16_bf16(a1, b0, acc[1][0], 0, 0, 0);
            acc[1][1] = __builtin_amdgcn_mfma_f32_32x32x16_bf16(a1, b1, acc[1][1], 0, 0, 0);
        }
        __syncthreads();
    }

    // epilogue: C/D layout col=lane&31, row=(reg&3)+8*(reg>>2)+4*(lane>>5)
    float bv[2];
#pragma unroll
    for (int j = 0; j < 2; ++j) bv[j] = bias[bn + wn + j * 32 + row32];
#pragma unroll
    for (int i = 0; i < 2; ++i)
#pragma unroll
        for (int j = 0; j < 2; ++j)
#pragma unroll
            for (int r = 0; r < 16; ++r) {
                int row = bm + wm + i * 32 + (r & 3) + 8 * (r >> 2) + 4 * half;
                int col = bn + wn + j * 32 + row32;
                float v = acc[i][j][r] + bv[j];
                if (relu) v = fmaxf(v, 0.f);
                C[(size_t)row * ldc + col] = f2b(v);
            }
}

// ================= final: heads + physics + QP + softmax combine ===========
__global__ __launch_bounds__(256)
void k_final(const u16* __restrict__ x51b, const u16* __restrict__ x52b,
             const float* __restrict__ x, const float* __restrict__ mean,
             const float* __restrict__ std_, const float* __restrict__ mean_label,
             const float* __restrict__ std_label, const float* __restrict__ wt,
             float* __restrict__ out) {
    int b = blockIdx.x * blockDim.x + threadIdx.x;   // < 16384

    float w[10], m = -1e30f;
#pragma unroll
    for (int h = 0; h < 10; ++h) { w[h] = wt[h]; m = fmaxf(m, w[h]); }
    float s = 0.f;
#pragma unroll
    for (int h = 0; h < 10; ++h) { w[h] = __expf(w[h] - m); s += w[h]; }
    float winv = 1.f / s;

    float4 xv = ((const float4*)x)[b];
    float th1 = xv.x * std_[0] + mean[0];
    float w1v = xv.y * std_[1] + mean[1];
    float th2 = xv.z * std_[2] + mean[2];
    float w2v = xv.w * std_[3] + mean[3];
    float s1 = sinf(th1), c1 = cosf(th1);
    float s2 = sinf(th2), c2 = cosf(th2);
    float px = 3.f * c1 + 3.f * c2 - 0.f;
    float py = 3.f * s1 + 3.f * s2 - 7.f;
    float vx = -3.f * s1 * w1v - 3.f * s2 * w2v;
    float vy =  3.f * c1 * w1v + 3.f * c2 * w2v;
    float barrier = px * px + py * py - 16.f;
    float b_dot = 2.f * (px * vx + py * vy);
    float Lf2b = 2.f * vx * vx + 2.f * vy * vy
               + 2.f * px * (-3.f * c1 * w1v * w1v - 3.f * c2 * w2v * w2v)
               + 2.f * py * (-3.f * s1 * w1v * w1v - 3.f * s2 * w2v * w2v);
    float g1 = 2.f * px * (-3.f * s1) + 2.f * py * (3.f * c1);
    float g2 = 2.f * px * (-3.f * s2) + 2.f * py * (3.f * c2);
    float Gx = -g1, Gy = -g2;
    float Gdot = Gx * Gx + Gy * Gy;

    float alpha = 4.f / (1.f + expf(-b2f(x52b[(size_t)b * 128 + 0])));

    float rx = 0.f, ry = 0.f;
#pragma unroll
    for (int h = 0; h < 10; ++h) {
        float r0 = b2f(x51b[(size_t)b * 128 + 2 * h]);
        float r1 = b2f(x51b[(size_t)b * 128 + 2 * h + 1]);
        float beta = 4.f / (1.f + expf(-b2f(x52b[(size_t)b * 128 + 1 + h])));
        float hh = Lf2b + (alpha + beta) * b_dot + alpha * beta * barrier;
        float ux = -r0, uy = -r1;
        float viol = ux * Gx + uy * Gy - hh;
        float lam = fmaxf(viol / Gdot, 0.f);
        float sx = ux - lam * Gx;
        float sy = uy - lam * Gy;
        float wk = w[h] * winv;
        rx += wk * sx; ry += wk * sy;
    }
    out[2 * b]     = (rx - mean_label[0]) / std_label[0];
    out[2 * b + 1] = (ry - mean_label[1]) / std_label[1];
}

extern "C" void kernel_launch(void* const* d_in, const int* in_sizes, int n_in,
                              void* d_out, int out_size, void* d_ws, size_t ws_size,
                              hipStream_t stream) {
    const float* x    = (const float*)d_in[0];
    const float* mean = (const float*)d_in[2];
    const float* std_ = (const float*)d_in[3];
    const float* mean_label = (const float*)d_in[4];
    const float* std_label  = (const float*)d_in[5];
    const float* W1  = (const float*)d_in[6];
    const float* b1  = (const float*)d_in[7];
    const float* W2  = (const float*)d_in[8];
    const float* b2  = (const float*)d_in[9];
    const float* W31 = (const float*)d_in[10];
    const float* b31 = (const float*)d_in[11];
    const float* W32 = (const float*)d_in[12];
    const float* b32 = (const float*)d_in[13];
    const float* W41 = (const float*)d_in[14];
    const float* b41 = (const float*)d_in[15];
    const float* W42 = (const float*)d_in[16];
    const float* b42 = (const float*)d_in[17];
    const float* W51 = (const float*)d_in[18];
    const float* b51 = (const float*)d_in[19];
    const float* W52 = (const float*)d_in[20];
    const float* b52 = (const float*)d_in[21];
    const float* wt  = (const float*)d_in[22];

    const int B = in_sizes[0] / 4;       // 16384

    char* wsp = (char*)d_ws;
    size_t off = 0;
    auto alloc = [&](size_t bytes) {
        void* p = wsp + off;
        off += (bytes + 255) & ~(size_t)255;
        return p;
    };
    u16*   W2b  = (u16*)  alloc((size_t)2048 * 2048 * 2);
    u16*   W31b = (u16*)  alloc((size_t)1024 * 2048 * 2);  // W31b||W32b contiguous
    u16*   W32b = (u16*)  alloc((size_t)1024 * 2048 * 2);  //   = [2048][2048] weight
    u16*   W41b = (u16*)  alloc((size_t)1024 * 1024 * 2);
    u16*   W42b = (u16*)  alloc((size_t)1024 * 1024 * 2);
    u16*   W51p = (u16*)  alloc((size_t)128 * 1024 * 2);
    u16*   W52p = (u16*)  alloc((size_t)128 * 1024 * 2);
    float* b51p = (float*)alloc(512);
    float* b52p = (float*)alloc(512);
    float* b3c  = (float*)alloc(2048 * 4);
    u16*   bufA = (u16*)  alloc((size_t)B * 2048 * 2);   // h1 -> h31||h32
    u16*   bufB = (u16*)  alloc((size_t)B * 2048 * 2);   // h2 -> h41||h42
    u16*   bufC = (u16*)  alloc((size_t)B * 256 * 2);    // x51b | x52b
    u16* x51b = bufC;
    u16* x52b = bufC + (size_t)B * 128;
    const u16* NUL = nullptr;

    // fused weight prep + layer 1 (11528 blocks)
    k_prep<<<11528, 256, 0, stream>>>(
        W2, W2b, W31, W31b, W32, W32b, W41, W41b, W42, W42b,
        W51, W51p, b51, b51p, W52, W52p, b52, b52p,
        b31, b32, b3c, x, W1, b1, bufA);

    // L2: h2 = relu(h1 @ W2^T + b2)            [B,2048] -> bufB
    k_gemm<<<dim3(16, B / 128), 256, 0, stream>>>(
        bufA, W2b, b2, bufB, 2048, 2048, 2048, 1, NUL, NUL, nullptr, nullptr, 0);
    // L3 fused: h31||h32 = relu(h2 @ [W31;W32]^T + b3c)   -> bufA
    k_gemm<<<dim3(16, B / 128), 256, 0, stream>>>(
        bufB, W31b, b3c, bufA, 2048, 2048, 2048, 1, NUL, NUL, nullptr, nullptr, 0);
    // L4 fused (two GEMMs, one dispatch): h41 -> bufB[:, :1024], h42 -> bufB[:, 1024:]
    k_gemm<<<dim3(8, 2 * (B / 128)), 256, 0, stream>>>(
        bufA, W41b, b41, bufB, 1024, 2048, 2048, 1,
        bufA + 1024, W42b, b42, bufB + 1024, B / 128);
    // heads fused: x51b = h41 @ W51p^T + b51p; x52b = h42 @ W52p^T + b52p
    k_gemm<<<dim3(1, 2 * (B / 128)), 256, 0, stream>>>(
        bufB, W51p, b51p, x51b, 1024, 2048, 128, 0,
        bufB + 1024, W52p, b52p, x52b, B / 128);

    // final physics + QP + combine
    k_final<<<B / 256, 256, 0, stream>>>(x51b, x52b, x, mean, std_,
                                         mean_label, std_label, wt, (float*)d_out);
}

// Round 6
// 508.199 us; speedup vs baseline: 1.1052x; 1.1052x over previous
//
#include <hip/hip_runtime.h>

typedef unsigned short u16;
typedef unsigned int   u32;
typedef __attribute__((ext_vector_type(8)))  short short8;   // 8 bf16 (4 VGPRs)
typedef __attribute__((ext_vector_type(16))) float floatx16; // 32x32 MFMA C/D
typedef __attribute__((ext_vector_type(8)))  u16   u16x8;
typedef __attribute__((ext_vector_type(4)))  u16   u16x4;

__device__ __forceinline__ u16 f2b(float f) {
    u32 u = __float_as_uint(f);
    u = (u + 0x7FFFu + ((u >> 16) & 1u)) >> 16;
    return (u16)u;
}
__device__ __forceinline__ float b2f(u16 h) {
    return __uint_as_float(((u32)h) << 16);
}

// ================= prep building blocks (256-thread granularity) ===========
__device__ __forceinline__ void f2b_block(const float* __restrict__ src,
                                          u16* __restrict__ dst, int blk) {
    int i = blk * 256 + threadIdx.x;
    float4 v = ((const float4*)src)[i];
    u16x4 o;
    o[0] = f2b(v.x); o[1] = f2b(v.y); o[2] = f2b(v.z); o[3] = f2b(v.w);
    *(u16x4*)&dst[i * 4] = o;
}

__device__ __forceinline__ void pad_block(const float* __restrict__ Wsrc, int rows,
                                          u16* __restrict__ Wdst,
                                          const float* __restrict__ bsrc,
                                          float* __restrict__ bdst, int blk) {
    int i = blk * 256 + threadIdx.x;        // 32768 total (128x1024/4)
    int idx = i * 4;
    int r = idx >> 10;
    int c = idx & 1023;
    u16x4 o;
    if (r < rows) {
        float4 v = *(const float4*)&Wsrc[r * 1024 + c];
        o[0] = f2b(v.x); o[1] = f2b(v.y); o[2] = f2b(v.z); o[3] = f2b(v.w);
    } else {
        o[0] = 0; o[1] = 0; o[2] = 0; o[3] = 0;
    }
    *(u16x4*)&Wdst[idx] = o;
    if (i < 128) bdst[i] = (i < rows) ? bsrc[i] : 0.f;
}

__device__ __forceinline__ void l1_block(const float* __restrict__ x,
                                         const float* __restrict__ W1,
                                         const float* __restrict__ b1,
                                         u16* __restrict__ h1, int blk) {
    const int t  = threadIdx.x;
    const int b0 = blk * 16;
    const int n0 = t * 8;
    float4 wreg[8]; float breg[8];
    const float4* W14 = (const float4*)W1;
#pragma unroll
    for (int i = 0; i < 8; ++i) { wreg[i] = W14[n0 + i]; breg[i] = b1[n0 + i]; }
    for (int r = 0; r < 16; ++r) {
        int b = b0 + r;
        float4 xv = ((const float4*)x)[b];
        u16x8 o;
#pragma unroll
        for (int i = 0; i < 8; ++i) {
            float s = xv.x * wreg[i].x + xv.y * wreg[i].y +
                      xv.z * wreg[i].z + xv.w * wreg[i].w + breg[i];
            s = fmaxf(s, 0.f);
            o[i] = f2b(s);
        }
        *(u16x8*)&h1[(size_t)b * 2048 + n0] = o;
    }
}

// ===== stage-1 prep: only what gates the L2 GEMM (W2 convert + layer 1) ====
// blocks: W2 4096 | l1 1024 = 5120
__global__ __launch_bounds__(256)
void k_prep1(const float* W2, u16* W2b,
             const float* x, const float* W1, const float* b1, u16* h1) {
    int blk = blockIdx.x;
    if (blk < 4096) { f2b_block(W2, W2b, blk); return; }
    l1_block(x, W1, b1, h1, blk - 4096);
}

// ===== backfill prep (runs as extra blocks inside the L2 GEMM dispatch) ====
// pblk: [0,2048) W31 | [2048,4096) W32 | [4096,5120) W41 | [5120,6144) W42 |
//       [6144,6272) W51 pad | [6272,6400) W52 pad | [6400,6408) bcat | rest nop
__device__ __forceinline__ void backfill_prep(
        int pblk,
        const float* W31, u16* W31b, const float* W32, u16* W32b,
        const float* W41, u16* W41b, const float* W42, u16* W42b,
        const float* W51, u16* W51p, const float* b51, float* b51p,
        const float* W52, u16* W52p, const float* b52, float* b52p,
        const float* b31, const float* b32, float* b3c) {
    if (pblk < 2048) { f2b_block(W31, W31b, pblk); return; }   pblk -= 2048;
    if (pblk < 2048) { f2b_block(W32, W32b, pblk); return; }   pblk -= 2048;
    if (pblk < 1024) { f2b_block(W41, W41b, pblk); return; }   pblk -= 1024;
    if (pblk < 1024) { f2b_block(W42, W42b, pblk); return; }   pblk -= 1024;
    if (pblk < 128)  { pad_block(W51, 20, W51p, b51, b51p, pblk); return; } pblk -= 128;
    if (pblk < 128)  { pad_block(W52, 11, W52p, b52, b52p, pblk); return; } pblk -= 128;
    if (pblk < 8) {
        int i = pblk * 256 + threadIdx.x;
        b3c[i] = (i < 1024) ? b31[i] : b32[i - 1024];
    }
}

// ================= trunk bf16 MFMA GEMM: 256x128 tile, BK=64 ===============
// C[M,N] = act(A[M,K] @ W[N,K]^T + b). 256 threads = 4 waves; wave tile
// 128x64 via 4x2 of mfma_f32_32x32x16_bf16, 4 k-steps -> 32 MFMA and
// 24 ds_read_b128 per wave per barrier (vs 16/16 at 64x64 wave tile).
// global_load_lds 16B/lane staging; rows are 128 B (all 32 banks), chunks
// XOR-swizzled: physical chunk p at row r holds logical p ^ (r&7); staging
// permutes WHICH lane loads which global chunk (coalescing unchanged).
// acc = 128 regs -> launch_bounds(256,2): 2 waves/SIMD, 2 blocks/CU (48 KB LDS).
// XCD-aware swizzle over the GEMM portion of the grid; blocks beyond
// gemmY rows run backfill weight-prep (L2 dispatch only).
// Optional second GEMM (A2/W2/bias2/C2) for swizzled by >= split.
__global__ __launch_bounds__(256, 2)
void k_gemm256(const u16* __restrict__ A, const u16* __restrict__ W,
               const float* __restrict__ bias, u16* __restrict__ C,
               int K, int lda, int ldc, int relu, int gemmY,
               const u16* A2, const u16* W2g, const float* bias2, u16* C2,
               int split,
               const float* W31, u16* W31b, const float* W32, u16* W32b,
               const float* W41, u16* W41b, const float* W42, u16* W42b,
               const float* W51, u16* W51p, const float* b51, float* b51p,
               const float* W52, u16* W52p, const float* b52, float* b52p,
               const float* b31, const float* b32, float* b3c) {
    const int ngemm = gemmY * gridDim.x;
    int flat = blockIdx.y * gridDim.x + blockIdx.x;
    if (flat >= ngemm) {
        backfill_prep(flat - ngemm, W31, W31b, W32, W32b, W41, W41b,
                      W42, W42b, W51, W51p, b51, b51p, W52, W52p, b52, b52p,
                      b31, b32, b3c);
        return;
    }

    __shared__ __align__(16) u16 As[256 * 64];  // 32 KB
    __shared__ __align__(16) u16 Ws[128 * 64];  // 16 KB

    const int tid  = threadIdx.x;
    const int wave = tid >> 6;
    const int lane = tid & 63;

    // XCD swizzle (valid permutation when gemmY % 8 == 0)
    int xcd = flat & 7;
    int p   = flat >> 3;
    int bx  = p % gridDim.x;
    int by  = (p / gridDim.x) * 8 + xcd;

    if (A2 != nullptr && by >= split) {
        A = A2; W = W2g; bias = bias2; C = C2; by -= split;
    }
    const int bm = by * 256;
    const int bn = bx * 128;

    // staging: wave covers 8 rows x 128 B per issue. lane -> row lane>>3,
    // physical chunk lane&7 holding logical chunk (lane&7)^(lane>>3).
    const int srow = lane >> 3;                    // 0..7
    const int sg   = ((lane & 7) ^ srow) * 8;      // swizzled global k-elem offset

    const int wm    = (wave & 1) * 128;
    const int wn    = (wave >> 1) * 64;
    const int row32 = lane & 31;
    const int half  = lane >> 5;

    floatx16 acc[4][2];
#pragma unroll
    for (int i = 0; i < 4; ++i)
#pragma unroll
        for (int j = 0; j < 2; ++j)
#pragma unroll
            for (int r = 0; r < 16; ++r) acc[i][j][r] = 0.f;

    for (int k0 = 0; k0 < K; k0 += 64) {
#pragma unroll
        for (int i = 0; i < 8; ++i) {
            int ci = wave * 8 + i;              // 32 chunks of 8 rows (A)
            int r  = ci * 8 + srow;
            const u16* ga = A + (size_t)(bm + r) * lda + k0 + sg;
            __builtin_amdgcn_global_load_lds(
                (const __attribute__((address_space(1))) void*)ga,
                (__attribute__((address_space(3))) void*)&As[ci * 512], 16, 0, 0);
        }
#pragma unroll
        for (int i = 0; i < 4; ++i) {
            int ci = wave * 4 + i;              // 16 chunks of 8 rows (W)
            int r  = ci * 8 + srow;
            const u16* gw = W + (size_t)(bn + r) * K + k0 + sg;
            __builtin_amdgcn_global_load_lds(
                (const __attribute__((address_space(1))) void*)gw,
                (__attribute__((address_space(3))) void*)&Ws[ci * 512], 16, 0, 0);
        }
        __syncthreads();

#pragma unroll
        for (int s = 0; s < 4; ++s) {
            const int c = s * 2 + half;         // logical 16B chunk 0..7
            short8 af[4], bf[2];
#pragma unroll
            for (int i = 0; i < 4; ++i) {
                int r = wm + i * 32 + row32;
                af[i] = *(const short8*)&As[r * 64 + ((c ^ (r & 7)) * 8)];
            }
#pragma unroll
            for (int j = 0; j < 2; ++j) {
                int r = wn + j * 32 + row32;
                bf[j] = *(const short8*)&Ws[r * 64 + ((c ^ (r & 7)) * 8)];
            }
#pragma unroll
            for (int i = 0; i < 4; ++i)
#pragma unroll
                for (int j = 0; j < 2; ++j)
                    acc[i][j] = __builtin_amdgcn_mfma_f32_32x32x16_bf16(
                        af[i], bf[j], acc[i][j], 0, 0, 0);
        }
        __syncthreads();
    }

    // epilogue: C/D layout col=lane&31, row=(reg&3)+8*(reg>>2)+4*(lane>>5)
    float bv[2];
#pragma unroll
    for (int j = 0; j < 2; ++j) bv[j] = bias[bn + wn + j * 32 + row32];
#pragma unroll
    for (int i = 0; i < 4; ++i)
#pragma unroll
        for (int j = 0; j < 2; ++j)
#pragma unroll
            for (int r = 0; r < 16; ++r) {
                int row = bm + wm + i * 32 + (r & 3) + 8 * (r >> 2) + 4 * half;
                int col = bn + wn + j * 32 + row32;
                float v = acc[i][j][r] + bv[j];
                if (relu) v = fmaxf(v, 0.f);
                C[(size_t)row * ldc + col] = f2b(v);
            }
}

// ================= heads bf16 MFMA GEMM: 128x128 tile, BK=64 (R3 struct) ===
__global__ __launch_bounds__(256, 4)
void k_gemm(const u16* __restrict__ A, const u16* __restrict__ W,
            const float* __restrict__ bias, u16* __restrict__ C,
            int K, int lda, int ldc, int relu,
            const u16* A2, const u16* W2, const float* bias2, u16* C2,
            int split) {
    __shared__ __align__(16) u16 As[128 * 64];  // 16 KB
    __shared__ __align__(16) u16 Ws[128 * 64];  // 16 KB

    const int tid  = threadIdx.x;
    const int wave = tid >> 6;
    const int lane = tid & 63;

    int by, bx;
    {
        int flat = blockIdx.y * gridDim.x + blockIdx.x;
        int xcd  = flat & 7;
        int p    = flat >> 3;
        bx = p % gridDim.x;
        by = (p / gridDim.x) * 8 + xcd;
    }
    if (A2 != nullptr && by >= split) {
        A = A2; W = W2; bias = bias2; C = C2; by -= split;
    }
    const int bm = by * 128;
    const int bn = bx * 128;

    const int srow = lane >> 3;
    const int sg   = ((lane & 7) ^ srow) * 8;

    const int wm    = (wave & 1) * 64;
    const int wn    = (wave >> 1) * 64;
    const int row32 = lane & 31;
    const int half  = lane >> 5;

    floatx16 acc[2][2];
#pragma unroll
    for (int i = 0; i < 2; ++i)
#pragma unroll
        for (int j = 0; j < 2; ++j)
#pragma unroll
            for (int r = 0; r < 16; ++r) acc[i][j][r] = 0.f;

    for (int k0 = 0; k0 < K; k0 += 64) {
#pragma unroll
        for (int i = 0; i < 4; ++i) {
            int ci = wave * 4 + i;
            int r  = ci * 8 + srow;
            const u16* ga = A + (size_t)(bm + r) * lda + k0 + sg;
            __builtin_amdgcn_global_load_lds(
                (const __attribute__((address_space(1))) void*)ga,
                (__attribute__((address_space(3))) void*)&As[ci * 512], 16, 0, 0);
            const u16* gw = W + (size_t)(bn + r) * K + k0 + sg;
            __builtin_amdgcn_global_load_lds(
                (const __attribute__((address_space(1))) void*)gw,
                (__attribute__((address_space(3))) void*)&Ws[ci * 512], 16, 0, 0);
        }
        __syncthreads();

#pragma unroll
        for (int s = 0; s < 4; ++s) {
            const int c = s * 2 + half;
            short8 a0, a1, b0, b1;
            { int r = wm + row32;       a0 = *(const short8*)&As[r * 64 + ((c ^ (r & 7)) * 8)]; }
            { int r = wm + 32 + row32;  a1 = *(const short8*)&As[r * 64 + ((c ^ (r & 7)) * 8)]; }
            { int r = wn + row32;       b0 = *(const short8*)&Ws[r * 64 + ((c ^ (r & 7)) * 8)]; }
            { int r = wn + 32 + row32;  b1 = *(const short8*)&Ws[r * 64 + ((c ^ (r & 7)) * 8)]; }
            acc[0][0] = __builtin_amdgcn_mfma_f32_32x32x16_bf16(a0, b0, acc[0][0], 0, 0, 0);
            acc[0][1] = __builtin_amdgcn_mfma_f32_32x32x16_bf16(a0, b1, acc[0][1], 0, 0, 0);
            acc[1][0] = __builtin_amdgcn_mfma_f32_32x32x16_bf16(a1, b0, acc[1][0], 0, 0, 0);
            acc[1][1] = __builtin_amdgcn_mfma_f32_32x32x16_bf16(a1, b1, acc[1][1], 0, 0, 0);
        }
        __syncthreads();
    }

    float bv[2];
#pragma unroll
    for (int j = 0; j < 2; ++j) bv[j] = bias[bn + wn + j * 32 + row32];
#pragma unroll
    for (int i = 0; i < 2; ++i)
#pragma unroll
        for (int j = 0; j < 2; ++j)
#pragma unroll
            for (int r = 0; r < 16; ++r) {
                int row = bm + wm + i * 32 + (r & 3) + 8 * (r >> 2) + 4 * half;
                int col = bn + wn + j * 32 + row32;
                float v = acc[i][j][r] + bv[j];
                if (relu) v = fmaxf(v, 0.f);
                C[(size_t)row * ldc + col] = f2b(v);
            }
}

// ================= final: heads + physics + QP + softmax combine ===========
__global__ __launch_bounds__(256)
void k_final(const u16* __restrict__ x51b, const u16* __restrict__ x52b,
             const float* __restrict__ x, const float* __restrict__ mean,
             const float* __restrict__ std_, const float* __restrict__ mean_label,
             const float* __restrict__ std_label, const float* __restrict__ wt,
             float* __restrict__ out) {
    int b = blockIdx.x * blockDim.x + threadIdx.x;   // < 16384

    float w[10], m = -1e30f;
#pragma unroll
    for (int h = 0; h < 10; ++h) { w[h] = wt[h]; m = fmaxf(m, w[h]); }
    float s = 0.f;
#pragma unroll
    for (int h = 0; h < 10; ++h) { w[h] = __expf(w[h] - m); s += w[h]; }
    float winv = 1.f / s;

    float4 xv = ((const float4*)x)[b];
    float th1 = xv.x * std_[0] + mean[0];
    float w1v = xv.y * std_[1] + mean[1];
    float th2 = xv.z * std_[2] + mean[2];
    float w2v = xv.w * std_[3] + mean[3];
    float s1 = sinf(th1), c1 = cosf(th1);
    float s2 = sinf(th2), c2 = cosf(th2);
    float px = 3.f * c1 + 3.f * c2 - 0.f;
    float py = 3.f * s1 + 3.f * s2 - 7.f;
    float vx = -3.f * s1 * w1v - 3.f * s2 * w2v;
    float vy =  3.f * c1 * w1v + 3.f * c2 * w2v;
    float barrier = px * px + py * py - 16.f;
    float b_dot = 2.f * (px * vx + py * vy);
    float Lf2b = 2.f * vx * vx + 2.f * vy * vy
               + 2.f * px * (-3.f * c1 * w1v * w1v - 3.f * c2 * w2v * w2v)
               + 2.f * py * (-3.f * s1 * w1v * w1v - 3.f * s2 * w2v * w2v);
    float g1 = 2.f * px * (-3.f * s1) + 2.f * py * (3.f * c1);
    float g2 = 2.f * px * (-3.f * s2) + 2.f * py * (3.f * c2);
    float Gx = -g1, Gy = -g2;
    float Gdot = Gx * Gx + Gy * Gy;

    float alpha = 4.f / (1.f + expf(-b2f(x52b[(size_t)b * 128 + 0])));

    float rx = 0.f, ry = 0.f;
#pragma unroll
    for (int h = 0; h < 10; ++h) {
        float r0 = b2f(x51b[(size_t)b * 128 + 2 * h]);
        float r1 = b2f(x51b[(size_t)b * 128 + 2 * h + 1]);
        float beta = 4.f / (1.f + expf(-b2f(x52b[(size_t)b * 128 + 1 + h])));
        float hh = Lf2b + (alpha + beta) * b_dot + alpha * beta * barrier;
        float ux = -r0, uy = -r1;
        float viol = ux * Gx + uy * Gy - hh;
        float lam = fmaxf(viol / Gdot, 0.f);
        float sx = ux - lam * Gx;
        float sy = uy - lam * Gy;
        float wk = w[h] * winv;
        rx += wk * sx; ry += wk * sy;
    }
    out[2 * b]     = (rx - mean_label[0]) / std_label[0];
    out[2 * b + 1] = (ry - mean_label[1]) / std_label[1];
}

extern "C" void kernel_launch(void* const* d_in, const int* in_sizes, int n_in,
                              void* d_out, int out_size, void* d_ws, size_t ws_size,
                              hipStream_t stream) {
    const float* x    = (const float*)d_in[0];
    const float* mean = (const float*)d_in[2];
    const float* std_ = (const float*)d_in[3];
    const float* mean_label = (const float*)d_in[4];
    const float* std_label  = (const float*)d_in[5];
    const float* W1  = (const float*)d_in[6];
    const float* b1  = (const float*)d_in[7];
    const float* W2  = (const float*)d_in[8];
    const float* b2  = (const float*)d_in[9];
    const float* W31 = (const float*)d_in[10];
    const float* b31 = (const float*)d_in[11];
    const float* W32 = (const float*)d_in[12];
    const float* b32 = (const float*)d_in[13];
    const float* W41 = (const float*)d_in[14];
    const float* b41 = (const float*)d_in[15];
    const float* W42 = (const float*)d_in[16];
    const float* b42 = (const float*)d_in[17];
    const float* W51 = (const float*)d_in[18];
    const float* b51 = (const float*)d_in[19];
    const float* W52 = (const float*)d_in[20];
    const float* b52 = (const float*)d_in[21];
    const float* wt  = (const float*)d_in[22];

    const int B = in_sizes[0] / 4;       // 16384

    char* wsp = (char*)d_ws;
    size_t off = 0;
    auto alloc = [&](size_t bytes) {
        void* p = wsp + off;
        off += (bytes + 255) & ~(size_t)255;
        return p;
    };
    u16*   W2b  = (u16*)  alloc((size_t)2048 * 2048 * 2);
    u16*   W31b = (u16*)  alloc((size_t)1024 * 2048 * 2);  // W31b||W32b contiguous
    u16*   W32b = (u16*)  alloc((size_t)1024 * 2048 * 2);  //   = [2048][2048] weight
    u16*   W41b = (u16*)  alloc((size_t)1024 * 1024 * 2);
    u16*   W42b = (u16*)  alloc((size_t)1024 * 1024 * 2);
    u16*   W51p = (u16*)  alloc((size_t)128 * 1024 * 2);
    u16*   W52p = (u16*)  alloc((size_t)128 * 1024 * 2);
    float* b51p = (float*)alloc(512);
    float* b52p = (float*)alloc(512);
    float* b3c  = (float*)alloc(2048 * 4);
    u16*   bufA = (u16*)  alloc((size_t)B * 2048 * 2);   // h1 -> h31||h32
    u16*   bufB = (u16*)  alloc((size_t)B * 2048 * 2);   // h2 -> h41||h42
    u16*   bufC = (u16*)  alloc((size_t)B * 256 * 2);    // x51b | x52b
    u16* x51b = bufC;
    u16* x52b = bufC + (size_t)B * 128;
    const u16* NUL = nullptr;

    // stage-1 prep: W2 conversion + layer 1 (gates L2)
    k_prep1<<<5120, 256, 0, stream>>>(W2, W2b, x, W1, b1, bufA);

    // L2: h2 = relu(h1 @ W2^T + b2)  [B,2048] -> bufB
    // grid: 16 x (64 GEMM y-groups + 401 backfill rows = 6416 prep blocks)
    k_gemm256<<<dim3(16, 64 + 401), 256, 0, stream>>>(
        bufA, W2b, b2, bufB, 2048, 2048, 2048, 1, 64,
        NUL, NUL, nullptr, nullptr, 0,
        W31, W31b, W32, W32b, W41, W41b, W42, W42b,
        W51, W51p, b51, b51p, W52, W52p, b52, b52p, b31, b32, b3c);
    // L3 fused: h31||h32 = relu(h2 @ [W31;W32]^T + b3c) -> bufA
    k_gemm256<<<dim3(16, 64), 256, 0, stream>>>(
        bufB, W31b, b3c, bufA, 2048, 2048, 2048, 1, 64,
        NUL, NUL, nullptr, nullptr, 0,
        nullptr, nullptr, nullptr, nullptr, nullptr, nullptr, nullptr, nullptr,
        nullptr, nullptr, nullptr, nullptr, nullptr, nullptr, nullptr, nullptr,
        nullptr, nullptr, nullptr);
    // L4 fused: h41 -> bufB[:, :1024], h42 -> bufB[:, 1024:]
    k_gemm256<<<dim3(8, 128), 256, 0, stream>>>(
        bufA, W41b, b41, bufB, 1024, 2048, 2048, 1, 128,
        bufA + 1024, W42b, b42, bufB + 1024, 64,
        nullptr, nullptr, nullptr, nullptr, nullptr, nullptr, nullptr, nullptr,
        nullptr, nullptr, nullptr, nullptr, nullptr, nullptr, nullptr, nullptr,
        nullptr, nullptr, nullptr);
    // heads fused (128x128 kernel): x51b = h41 @ W51p^T; x52b = h42 @ W52p^T
    k_gemm<<<dim3(1, 2 * (B / 128)), 256, 0, stream>>>(
        bufB, W51p, b51p, x51b, 1024, 2048, 128, 0,
        bufB + 1024, W52p, b52p, x52b, B / 128);

    // final physics + QP + combine
    k_final<<<B / 256, 256, 0, stream>>>(x51b, x52b, x, mean, std_,
                                         mean_label, std_label, wt, (float*)d_out);
}